// Round 2
// baseline (601.658 us; speedup 1.0000x reference)
//
#include <hip/hip_runtime.h>

typedef __attribute__((ext_vector_type(8))) short short8;
typedef __attribute__((ext_vector_type(4))) float f32x4;

#define C_DIM 128
#define K_CODES 1024
#define TOT 8388608   // 16*128*64*64

__device__ __forceinline__ unsigned int f2bf1(float f) {
  unsigned int u = __float_as_uint(f);
  return (u + 0x7FFFu + ((u >> 16) & 1u)) >> 16;   // RNE fp32->bf16
}
__device__ __forceinline__ unsigned int f2bf2(float lo, float hi) {
  return f2bf1(lo) | (f2bf1(hi) << 16);
}

// ---- P: bf16 codebook + ||e||^2 + zero used/loss/counter (fused) ----
__global__ void prep_kernel(const float* __restrict__ cb,
                            unsigned short* __restrict__ ebf,
                            float* __restrict__ nsq,
                            int* __restrict__ used,
                            float* __restrict__ lossp,
                            int* __restrict__ counter) {
  int gid = blockIdx.x * 256 + threadIdx.x;     // grid 512*256 == K*C exactly
  ebf[gid] = (unsigned short)f2bf1(cb[gid]);
  if (gid < K_CODES) {
    float s = 0.f;
    #pragma unroll 8
    for (int c = 0; c < C_DIM; ++c) { float v = cb[gid * C_DIM + c]; s += v * v; }
    nsq[gid] = s;
    used[gid] = 0;
  }
  if (gid == 0) { *lossp = 0.0f; *counter = 0; }
}

// ---- M: per-(b,h) block: 64 pixels x 1024 codes argmin + gather + loss ----
// A-frag (16x16x32 bf16): lane L: m=L&15, k=(L>>4)*8+j ; B: n=L&15, k=(L>>4)*8+j
// D: col n = L&15, row m = (L>>4)*4 + reg
// B fragments are loaded DIRECTLY from global (L2-hot 256KB codebook): a wave's
// 64 lanes cover one contiguous 4KB slice -> coalesced dwordx4, no LDS, no
// barriers in the K loop.
__global__ __launch_bounds__(256, 4)
void vq_main(const float* __restrict__ zin, const float* __restrict__ cb,
             const unsigned short* __restrict__ ebf,
             const float* __restrict__ nsq,
             int* __restrict__ used, float* __restrict__ lossp,
             int* __restrict__ counter,
             float* __restrict__ out) {
  __shared__ __align__(16) unsigned char smem[16384];   // A granules
  __shared__ float nsq_s[K_CODES];
  __shared__ float redv[256];      // [pixel][wave]
  __shared__ int   redi[256];
  __shared__ int   widx[64];
  __shared__ float wsum[4];
  __shared__ int   us4[4];
  __shared__ int   lastflag;

  uint4* aG = (uint4*)smem;

  const int t  = threadIdx.x;
  const int L  = t & 63;
  const int wv = t >> 6;        // wave id 0..3
  const int q  = L >> 4;        // lane quad
  const int nL = L & 15;

  const int bb = blockIdx.x >> 6;
  const int h  = blockIdx.x & 63;
  const int zbase = bb * (C_DIM * 4096) + h * 64;   // + c*4096 + w

  for (int i = t; i < K_CODES; i += 256) nsq_s[i] = nsq[i];

  // ---- stage A granules: granule(ks,mt,q,mL) = z[c=ks*32+q*8+j][w=mt*16+mL] bf16
  // index = ks*256 + mt*64 + q*16 + ((mL + 4*(mt+q)) & 15)
  {
    const int w = t & 63;
    const int mt = w >> 4, mL_ = w & 15;
    #pragma unroll
    for (int p = 0; p < 4; ++p) {
      int oct = p * 4 + wv;                 // wave-uniform -> coalesced loads
      int ks = oct >> 2, qq = oct & 3;
      int c8 = oct * 8;
      float v[8];
      #pragma unroll
      for (int u = 0; u < 8; ++u) v[u] = zin[zbase + (c8 + u) * 4096 + w];
      uint4 val;
      val.x = f2bf2(v[0], v[1]); val.y = f2bf2(v[2], v[3]);
      val.z = f2bf2(v[4], v[5]); val.w = f2bf2(v[6], v[7]);
      int sA = (mL_ + 4 * (mt + qq)) & 15;
      aG[ks * 256 + mt * 64 + qq * 16 + sA] = val;
    }
  }
  __syncthreads();

  // ---- A fragments -> registers (reused across all 16 code tiles of this wave)
  short8 afrag[16];
  {
    const short8* ap = (const short8*)aG;
    #pragma unroll
    for (int mt = 0; mt < 4; ++mt)
      #pragma unroll
      for (int ks = 0; ks < 4; ++ks) {
        int sA = (nL + 4 * (mt + q)) & 15;
        afrag[mt * 4 + ks] = ap[ks * 256 + mt * 64 + q * 16 + sA];
      }
  }

  float minv[16]; int mini[16];
  #pragma unroll
  for (int i = 0; i < 16; ++i) { minv[i] = 3.0e38f; mini[i] = 0; }

  // ---- main loop: 16 code tiles per wave, B straight from global (no barriers)
  const short8* __restrict__ ebs = (const short8*)ebf;   // 16B granules
  #pragma unroll 2
  for (int j = 0; j < 16; ++j) {
    const int kb = (wv * 16 + j) * 16;
    const int row = kb + nL;                 // this lane's code
    const long rb = (long)row * 16;
    short8 b0 = ebs[rb + 0 * 4 + q];
    short8 b1 = ebs[rb + 1 * 4 + q];
    short8 b2 = ebs[rb + 2 * 4 + q];
    short8 b3 = ebs[rb + 3 * 4 + q];
    const float nv = nsq_s[row];
    f32x4 a0 = {0.f,0.f,0.f,0.f}, a1 = {0.f,0.f,0.f,0.f};
    f32x4 a2 = {0.f,0.f,0.f,0.f}, a3 = {0.f,0.f,0.f,0.f};
    a0 = __builtin_amdgcn_mfma_f32_16x16x32_bf16(afrag[0*4+0], b0, a0, 0,0,0);
    a1 = __builtin_amdgcn_mfma_f32_16x16x32_bf16(afrag[1*4+0], b0, a1, 0,0,0);
    a2 = __builtin_amdgcn_mfma_f32_16x16x32_bf16(afrag[2*4+0], b0, a2, 0,0,0);
    a3 = __builtin_amdgcn_mfma_f32_16x16x32_bf16(afrag[3*4+0], b0, a3, 0,0,0);
    a0 = __builtin_amdgcn_mfma_f32_16x16x32_bf16(afrag[0*4+1], b1, a0, 0,0,0);
    a1 = __builtin_amdgcn_mfma_f32_16x16x32_bf16(afrag[1*4+1], b1, a1, 0,0,0);
    a2 = __builtin_amdgcn_mfma_f32_16x16x32_bf16(afrag[2*4+1], b1, a2, 0,0,0);
    a3 = __builtin_amdgcn_mfma_f32_16x16x32_bf16(afrag[3*4+1], b1, a3, 0,0,0);
    a0 = __builtin_amdgcn_mfma_f32_16x16x32_bf16(afrag[0*4+2], b2, a0, 0,0,0);
    a1 = __builtin_amdgcn_mfma_f32_16x16x32_bf16(afrag[1*4+2], b2, a1, 0,0,0);
    a2 = __builtin_amdgcn_mfma_f32_16x16x32_bf16(afrag[2*4+2], b2, a2, 0,0,0);
    a3 = __builtin_amdgcn_mfma_f32_16x16x32_bf16(afrag[3*4+2], b2, a3, 0,0,0);
    a0 = __builtin_amdgcn_mfma_f32_16x16x32_bf16(afrag[0*4+3], b3, a0, 0,0,0);
    a1 = __builtin_amdgcn_mfma_f32_16x16x32_bf16(afrag[1*4+3], b3, a1, 0,0,0);
    a2 = __builtin_amdgcn_mfma_f32_16x16x32_bf16(afrag[2*4+3], b3, a2, 0,0,0);
    a3 = __builtin_amdgcn_mfma_f32_16x16x32_bf16(afrag[3*4+3], b3, a3, 0,0,0);
    #pragma unroll
    for (int r = 0; r < 4; ++r) {
      float d0 = nv - 2.0f * a0[r];
      if (d0 < minv[0*4+r]) { minv[0*4+r] = d0; mini[0*4+r] = row; }
      float d1 = nv - 2.0f * a1[r];
      if (d1 < minv[1*4+r]) { minv[1*4+r] = d1; mini[1*4+r] = row; }
      float d2 = nv - 2.0f * a2[r];
      if (d2 < minv[2*4+r]) { minv[2*4+r] = d2; mini[2*4+r] = row; }
      float d3 = nv - 2.0f * a3[r];
      if (d3 < minv[3*4+r]) { minv[3*4+r] = d3; mini[3*4+r] = row; }
    }
  }

  // ---- in-wave butterfly argmin over the 16 code-lanes of each quad
  #pragma unroll
  for (int m = 1; m <= 8; m <<= 1) {
    #pragma unroll
    for (int i = 0; i < 16; ++i) {
      float ov = __shfl_xor(minv[i], m, 64);
      int   oi = __shfl_xor(mini[i], m, 64);
      if (ov < minv[i] || (ov == minv[i] && oi < mini[i])) {
        minv[i] = ov; mini[i] = oi;          // jnp first-min tie-break
      }
    }
  }
  if (nL == 0) {
    #pragma unroll
    for (int mt = 0; mt < 4; ++mt)
      #pragma unroll
      for (int r = 0; r < 4; ++r) {
        int w = mt * 16 + q * 4 + r;         // pixel index
        redv[w * 4 + wv] = minv[mt * 4 + r];
        redi[w * 4 + wv] = mini[mt * 4 + r];
      }
  }
  __syncthreads();

  // ---- cross-wave final argmin (wave wv covers codes [wv*256, wv*256+256))
  if (t < 64) {
    float bv = redv[t * 4]; int bi = redi[t * 4];
    #pragma unroll
    for (int e = 1; e < 4; ++e) {
      float v = redv[t * 4 + e]; int ii = redi[t * 4 + e];
      if (v < bv || (v == bv && ii < bi)) { bv = v; bi = ii; }
    }
    widx[t] = bi;
    atomicOr(&used[bi], 1);                  // device-scope for cross-XCD read
  }
  __syncthreads();

  // ---- fp32 gather z_q + coalesced write + loss partial
  float lsum = 0.f;
  {
    const int w = t & 63, c0 = t >> 6;
    const int idx = widx[w];
    const float4* erow4 = (const float4*)(cb + idx * C_DIM);
    const int obase = zbase + w;
    #pragma unroll 2
    for (int i8 = 0; i8 < 8; ++i8) {
      float4 ev = erow4[c0 * 8 + i8];
      int c = c0 * 32 + i8 * 4;
      #pragma unroll
      for (int u = 0; u < 4; ++u) {
        float e = (&ev.x)[u];
        int off = obase + (c + u) * 4096;
        float d = zin[off] - e;
        out[off] = e;                        // lanes over w -> coalesced
        lsum += d * d;
      }
    }
  }
  #pragma unroll
  for (int o = 32; o > 0; o >>= 1) lsum += __shfl_down(lsum, o, 64);
  if (L == 0) wsum[wv] = lsum;
  __syncthreads();
  if (t == 0) atomicAdd(lossp, wsum[0] + wsum[1] + wsum[2] + wsum[3]);

  // ---- last-block finalize (device-scope atomics; per-XCD L2 not coherent)
  __threadfence();
  if (t == 0) { int old = atomicAdd(counter, 1); lastflag = (old == 1023) ? 1 : 0; }
  __syncthreads();
  if (lastflag) {
    int s = 0;
    for (int i = t; i < K_CODES; i += 256)
      s += (atomicAdd(&used[i], 0) != 0) ? 1 : 0;     // atomic read (coherent)
    #pragma unroll
    for (int o = 32; o > 0; o >>= 1) s += __shfl_down(s, o, 64);
    if (L == 0) us4[wv] = s;
    __syncthreads();
    if (t == 0) {
      float lt = atomicAdd(lossp, 0.0f);              // atomic read (coherent)
      out[TOT]     = 1.25f * lt / (float)TOT;         // (1+0.25)*MSE
      out[TOT + 1] = (float)(us4[0] + us4[1] + us4[2] + us4[3]) / 1024.0f;
    }
  }
}

extern "C" void kernel_launch(void* const* d_in, const int* in_sizes, int n_in,
                              void* d_out, int out_size, void* d_ws, size_t ws_size,
                              hipStream_t stream) {
  const float* z  = (const float*)d_in[0];
  const float* cb = (const float*)d_in[1];
  float* out = (float*)d_out;
  char* ws = (char*)d_ws;
  unsigned short* ebf = (unsigned short*)ws;          // 262144 B
  float* nsq   = (float*)(ws + 262144);               // 4096 B
  int*   used  = (int*)(ws + 266240);                 // 4096 B
  float* lossp = (float*)(ws + 270336);               // 4 B
  int*   counter = (int*)(ws + 270340);               // 4 B

  hipLaunchKernelGGL(prep_kernel, dim3(512), dim3(256), 0, stream,
                     cb, ebf, nsq, used, lossp, counter);
  hipLaunchKernelGGL(vq_main, dim3(1024), dim3(256), 0, stream,
                     z, cb, ebf, nsq, used, lossp, counter, out);
}

// Round 3
// 151.616 us; speedup vs baseline: 3.9683x; 3.9683x over previous
//
#include <hip/hip_runtime.h>

typedef __attribute__((ext_vector_type(8))) short short8;
typedef __attribute__((ext_vector_type(4))) float f32x4;

#define C_DIM 128
#define K_CODES 1024
#define TOT 8388608   // 16*128*64*64

__device__ __forceinline__ unsigned int f2bf1(float f) {
  unsigned int u = __float_as_uint(f);
  return (u + 0x7FFFu + ((u >> 16) & 1u)) >> 16;   // RNE fp32->bf16
}
__device__ __forceinline__ unsigned int f2bf2(float lo, float hi) {
  return f2bf1(lo) | (f2bf1(hi) << 16);
}

// ---- P: bf16 codebook + ||e||^2 + zero used/loss (fused) ----
__global__ void prep_kernel(const float* __restrict__ cb,
                            unsigned short* __restrict__ ebf,
                            float* __restrict__ nsq,
                            int* __restrict__ used,
                            float* __restrict__ lossp) {
  int gid = blockIdx.x * 256 + threadIdx.x;     // grid 512*256 == K*C exactly
  ebf[gid] = (unsigned short)f2bf1(cb[gid]);
  if (gid < K_CODES) {
    float s = 0.f;
    #pragma unroll 8
    for (int c = 0; c < C_DIM; ++c) { float v = cb[gid * C_DIM + c]; s += v * v; }
    nsq[gid] = s;
    used[gid] = 0;
  }
  if (gid == 0) { *lossp = 0.0f; }
}

// ---- M: per-(b,h) block: 64 pixels x 1024 codes argmin + gather + loss ----
// A-frag (16x16x32 bf16): lane L: m=L&15, k=(L>>4)*8+j ; B: n=L&15, k=(L>>4)*8+j
// D: col n = L&15, row m = (L>>4)*4 + reg
// B fragments load DIRECTLY from global (L2-hot 256KB codebook): a wave's 64
// lanes cover one contiguous 4KB slice -> coalesced dwordx4, no K-loop barriers.
// launch_bounds(256,3): ~170 unified VGPR/wave — the ~140-reg live set
// (afrag 64 + minv/mini 32 + acc 16 + B 16 + addr) MUST NOT spill; (256,4)
// spilled to scratch and cost 1.5 GB of HBM traffic (round 2 post-mortem).
__global__ __launch_bounds__(256, 3)
void vq_main(const float* __restrict__ zin, const float* __restrict__ cb,
             const unsigned short* __restrict__ ebf,
             const float* __restrict__ nsq,
             int* __restrict__ used, float* __restrict__ lossp,
             float* __restrict__ out) {
  __shared__ __align__(16) unsigned char smem[16384];   // A granules
  __shared__ float nsq_s[K_CODES];
  __shared__ float redv[256];      // [pixel][wave]
  __shared__ int   redi[256];
  __shared__ int   widx[64];
  __shared__ float wsum[4];

  uint4* aG = (uint4*)smem;

  const int t  = threadIdx.x;
  const int L  = t & 63;
  const int wv = t >> 6;        // wave id 0..3
  const int q  = L >> 4;        // lane quad
  const int nL = L & 15;

  const int bb = blockIdx.x >> 6;
  const int h  = blockIdx.x & 63;
  const int zbase = bb * (C_DIM * 4096) + h * 64;   // + c*4096 + w

  for (int i = t; i < K_CODES; i += 256) nsq_s[i] = nsq[i];

  // ---- stage A granules: granule(ks,mt,q,mL) = z[c=ks*32+q*8+j][w=mt*16+mL] bf16
  // index = ks*256 + mt*64 + q*16 + ((mL + 4*(mt+q)) & 15)
  {
    const int w = t & 63;
    const int mt = w >> 4, mL_ = w & 15;
    #pragma unroll
    for (int p = 0; p < 4; ++p) {
      int oct = p * 4 + wv;                 // wave-uniform -> coalesced loads
      int ks = oct >> 2, qq = oct & 3;
      int c8 = oct * 8;
      float v[8];
      #pragma unroll
      for (int u = 0; u < 8; ++u) v[u] = zin[zbase + (c8 + u) * 4096 + w];
      uint4 val;
      val.x = f2bf2(v[0], v[1]); val.y = f2bf2(v[2], v[3]);
      val.z = f2bf2(v[4], v[5]); val.w = f2bf2(v[6], v[7]);
      int sA = (mL_ + 4 * (mt + qq)) & 15;
      aG[ks * 256 + mt * 64 + qq * 16 + sA] = val;
    }
  }
  __syncthreads();

  // ---- A fragments -> registers (reused across all 16 code tiles of this wave)
  short8 afrag[16];
  {
    const short8* ap = (const short8*)aG;
    #pragma unroll
    for (int mt = 0; mt < 4; ++mt)
      #pragma unroll
      for (int ks = 0; ks < 4; ++ks) {
        int sA = (nL + 4 * (mt + q)) & 15;
        afrag[mt * 4 + ks] = ap[ks * 256 + mt * 64 + q * 16 + sA];
      }
  }

  float minv[16]; int mini[16];
  #pragma unroll
  for (int i = 0; i < 16; ++i) { minv[i] = 3.0e38f; mini[i] = 0; }

  // ---- main loop: 16 code tiles per wave, B straight from global (no barriers)
  const short8* __restrict__ ebs = (const short8*)ebf;   // 16B granules
  for (int j = 0; j < 16; ++j) {
    const int kb = (wv * 16 + j) * 16;
    const int row = kb + nL;                 // this lane's code
    const long rb = (long)row * 16;
    short8 b0 = ebs[rb + 0 * 4 + q];
    short8 b1 = ebs[rb + 1 * 4 + q];
    short8 b2 = ebs[rb + 2 * 4 + q];
    short8 b3 = ebs[rb + 3 * 4 + q];
    const float nv = nsq_s[row];
    f32x4 a0 = {0.f,0.f,0.f,0.f}, a1 = {0.f,0.f,0.f,0.f};
    f32x4 a2 = {0.f,0.f,0.f,0.f}, a3 = {0.f,0.f,0.f,0.f};
    a0 = __builtin_amdgcn_mfma_f32_16x16x32_bf16(afrag[0*4+0], b0, a0, 0,0,0);
    a1 = __builtin_amdgcn_mfma_f32_16x16x32_bf16(afrag[1*4+0], b0, a1, 0,0,0);
    a2 = __builtin_amdgcn_mfma_f32_16x16x32_bf16(afrag[2*4+0], b0, a2, 0,0,0);
    a3 = __builtin_amdgcn_mfma_f32_16x16x32_bf16(afrag[3*4+0], b0, a3, 0,0,0);
    a0 = __builtin_amdgcn_mfma_f32_16x16x32_bf16(afrag[0*4+1], b1, a0, 0,0,0);
    a1 = __builtin_amdgcn_mfma_f32_16x16x32_bf16(afrag[1*4+1], b1, a1, 0,0,0);
    a2 = __builtin_amdgcn_mfma_f32_16x16x32_bf16(afrag[2*4+1], b1, a2, 0,0,0);
    a3 = __builtin_amdgcn_mfma_f32_16x16x32_bf16(afrag[3*4+1], b1, a3, 0,0,0);
    a0 = __builtin_amdgcn_mfma_f32_16x16x32_bf16(afrag[0*4+2], b2, a0, 0,0,0);
    a1 = __builtin_amdgcn_mfma_f32_16x16x32_bf16(afrag[1*4+2], b2, a1, 0,0,0);
    a2 = __builtin_amdgcn_mfma_f32_16x16x32_bf16(afrag[2*4+2], b2, a2, 0,0,0);
    a3 = __builtin_amdgcn_mfma_f32_16x16x32_bf16(afrag[3*4+2], b2, a3, 0,0,0);
    a0 = __builtin_amdgcn_mfma_f32_16x16x32_bf16(afrag[0*4+3], b3, a0, 0,0,0);
    a1 = __builtin_amdgcn_mfma_f32_16x16x32_bf16(afrag[1*4+3], b3, a1, 0,0,0);
    a2 = __builtin_amdgcn_mfma_f32_16x16x32_bf16(afrag[2*4+3], b3, a2, 0,0,0);
    a3 = __builtin_amdgcn_mfma_f32_16x16x32_bf16(afrag[3*4+3], b3, a3, 0,0,0);
    #pragma unroll
    for (int r = 0; r < 4; ++r) {
      float d0 = nv - 2.0f * a0[r];
      if (d0 < minv[0*4+r]) { minv[0*4+r] = d0; mini[0*4+r] = row; }
      float d1 = nv - 2.0f * a1[r];
      if (d1 < minv[1*4+r]) { minv[1*4+r] = d1; mini[1*4+r] = row; }
      float d2 = nv - 2.0f * a2[r];
      if (d2 < minv[2*4+r]) { minv[2*4+r] = d2; mini[2*4+r] = row; }
      float d3 = nv - 2.0f * a3[r];
      if (d3 < minv[3*4+r]) { minv[3*4+r] = d3; mini[3*4+r] = row; }
    }
  }

  // ---- in-wave butterfly argmin over the 16 code-lanes of each quad
  #pragma unroll
  for (int m = 1; m <= 8; m <<= 1) {
    #pragma unroll
    for (int i = 0; i < 16; ++i) {
      float ov = __shfl_xor(minv[i], m, 64);
      int   oi = __shfl_xor(mini[i], m, 64);
      if (ov < minv[i] || (ov == minv[i] && oi < mini[i])) {
        minv[i] = ov; mini[i] = oi;          // jnp first-min tie-break
      }
    }
  }
  if (nL == 0) {
    #pragma unroll
    for (int mt = 0; mt < 4; ++mt)
      #pragma unroll
      for (int r = 0; r < 4; ++r) {
        int w = mt * 16 + q * 4 + r;         // pixel index
        redv[w * 4 + wv] = minv[mt * 4 + r];
        redi[w * 4 + wv] = mini[mt * 4 + r];
      }
  }
  __syncthreads();

  // ---- cross-wave final argmin (wave wv covers codes [wv*256, wv*256+256))
  if (t < 64) {
    float bv = redv[t * 4]; int bi = redi[t * 4];
    #pragma unroll
    for (int e = 1; e < 4; ++e) {
      float v = redv[t * 4 + e]; int ii = redi[t * 4 + e];
      if (v < bv || (v == bv && ii < bi)) { bv = v; bi = ii; }
    }
    widx[t] = bi;
    used[bi] = 1;   // benign same-value race; kernel boundary = coherence point
  }
  __syncthreads();

  // ---- fp32 gather z_q + coalesced write + loss partial
  float lsum = 0.f;
  {
    const int w = t & 63, c0 = t >> 6;
    const int idx = widx[w];
    const float4* erow4 = (const float4*)(cb + idx * C_DIM);
    const int obase = zbase + w;
    #pragma unroll 2
    for (int i8 = 0; i8 < 8; ++i8) {
      float4 ev = erow4[c0 * 8 + i8];
      int c = c0 * 32 + i8 * 4;
      #pragma unroll
      for (int u = 0; u < 4; ++u) {
        float e = (&ev.x)[u];
        int off = obase + (c + u) * 4096;
        float d = zin[off] - e;
        out[off] = e;                        // lanes over w -> coalesced
        lsum += d * d;
      }
    }
  }
  #pragma unroll
  for (int o = 32; o > 0; o >>= 1) lsum += __shfl_down(lsum, o, 64);
  if (L == 0) wsum[wv] = lsum;
  __syncthreads();
  if (t == 0) atomicAdd(lossp, wsum[0] + wsum[1] + wsum[2] + wsum[3]);
}

// ---- F: usage count + loss finalize ----
__global__ void finalize_kernel(const int* __restrict__ used,
                                const float* __restrict__ lossp,
                                float* __restrict__ out2) {
  __shared__ int red[256];
  int t = threadIdx.x;
  int s = 0;
  for (int i = t; i < K_CODES; i += 256) s += (used[i] != 0) ? 1 : 0;
  red[t] = s;
  __syncthreads();
  for (int o = 128; o > 0; o >>= 1) {
    if (t < o) red[t] += red[t + o];
    __syncthreads();
  }
  if (t == 0) {
    out2[0] = 1.25f * lossp[0] / (float)TOT;  // (1+0.25)*MSE
    out2[1] = (float)red[0] / 1024.0f;
  }
}

extern "C" void kernel_launch(void* const* d_in, const int* in_sizes, int n_in,
                              void* d_out, int out_size, void* d_ws, size_t ws_size,
                              hipStream_t stream) {
  const float* z  = (const float*)d_in[0];
  const float* cb = (const float*)d_in[1];
  float* out = (float*)d_out;
  char* ws = (char*)d_ws;
  unsigned short* ebf = (unsigned short*)ws;          // 262144 B
  float* nsq   = (float*)(ws + 262144);               // 4096 B
  int*   used  = (int*)(ws + 266240);                 // 4096 B
  float* lossp = (float*)(ws + 270336);               // 4 B

  hipLaunchKernelGGL(prep_kernel, dim3(512), dim3(256), 0, stream,
                     cb, ebf, nsq, used, lossp);
  hipLaunchKernelGGL(vq_main, dim3(1024), dim3(256), 0, stream,
                     z, cb, ebf, nsq, used, lossp, out);
  hipLaunchKernelGGL(finalize_kernel, dim3(1), dim3(256), 0, stream,
                     used, lossp, out + TOT);
}